// Round 2
// baseline (374.579 us; speedup 1.0000x reference)
//
#include <hip/hip_runtime.h>
#include <stdint.h>
#include <math.h>

#define NH 16
#define DM 1024
#define SEQ 2048
#define DH 64
#define NB 4
// -1e9 premultiplied by log2(e): masked score -> exp2(-1.44e9) == 0
#define NEG2 (-1.4426950408889634e9f)
// (1/8) * log2(e)
#define SCL2 (0.18033688011112042f)

typedef __attribute__((ext_vector_type(8))) short bf16x8;
typedef __attribute__((ext_vector_type(4))) short bf16x4;
typedef __attribute__((ext_vector_type(4))) float f32x4;
typedef unsigned short u16;
typedef uint32_t u32;

__device__ __forceinline__ u16 f2bf(float f) {     // RNE
    union { float f; u32 i; } c; c.f = f;
    u32 r = c.i + 0x7fffu + ((c.i >> 16) & 1u);
    return (u16)(r >> 16);
}
// pack two f32 -> bf16x2 via RNE (pure C; no inline asm)
__device__ __forceinline__ u32 pk2(float lo, float hi) {
    return (u32)f2bf(lo) | ((u32)f2bf(hi) << 16);
}
// pack two f32 -> bf16x2 (round-half-up; inputs are exp() results, finite >=0)
__device__ __forceinline__ u32 packbf(float lo, float hi) {
    union { float f; u32 i; } a, b; a.f = lo; b.f = hi;
    return ((a.i + 0x8000u) >> 16) | ((b.i + 0x8000u) & 0xFFFF0000u);
}

__device__ __forceinline__ float fexp2(float x) {
#if __has_builtin(__builtin_amdgcn_exp2f)
    return __builtin_amdgcn_exp2f(x);
#else
    return exp2f(x);
#endif
}

__device__ __forceinline__ f32x4 pv_mfma(bf16x4 a, bf16x4 b, f32x4 c) {
#if __has_builtin(__builtin_amdgcn_mfma_f32_16x16x16bf16_1k)
    return __builtin_amdgcn_mfma_f32_16x16x16bf16_1k(a, b, c, 0, 0, 0);
#else
    f32x4 d;
    asm volatile("s_nop 1\n\t"
                 "v_mfma_f32_16x16x16_bf16 %0, %1, %2, %3\n\t"
                 "s_nop 7\n\t"
                 "s_nop 7"
                 : "=v"(d) : "v"(a), "v"(b), "v"(c));
    return d;
#endif
}

// fused: convert Wq,Wk,Wv (f32->bf16) + build mask floats. 3*1024 + 32 blocks.
__global__ __launch_bounds__(256) void prep_kernel(
    const float* __restrict__ Wq, const float* __restrict__ Wk,
    const float* __restrict__ Wv, const int* __restrict__ mask,
    u16* __restrict__ wqb, u16* __restrict__ wkb, u16* __restrict__ wvb,
    float* __restrict__ mf) {
    const int bid = blockIdx.x;
    if (bid < 3072) {
        const float* src = (bid < 1024) ? Wq : (bid < 2048) ? Wk : Wv;
        u16* dst = (bid < 1024) ? wqb : (bid < 2048) ? wkb : wvb;
        int i = (bid & 1023) * 256 + threadIdx.x;
        float4 v = ((const float4*)src)[i];
        ushort4 o = { f2bf(v.x), f2bf(v.y), f2bf(v.z), f2bf(v.w) };
        ((ushort4*)dst)[i] = o;
    } else {
        int i = (bid - 3072) * 256 + threadIdx.x;   // 32 blocks * 256 = 8192
        mf[i] = mask[i] ? 0.0f : NEG2;
    }
}

// Merged projection: grid (8, 192). blockIdx.y>>6 selects {Q,K,V}.
// C[8192,1024] = X[8192,1024](f32)*W[1024,1024]^T(bf16) (+bias), bf16 out.
// 128x128 tile, BK=32, LDS double-buffer, one barrier/iter. X converted
// f32->bf16 during staging (pure-C RNE pack, same rounding as round-0 cvt).
// LDS XOR swizzle (chunk ^= (row>>1)&3) spreads b128 reads across banks.
// which==2 (V): tile-blocked out[(((b*NH+h)*32+(s>>6))*DH+c)*64 + (s&63)]
__global__ __launch_bounds__(256, 3) void proj_kernel(
    const float* __restrict__ Qx, const float* __restrict__ Kx,
    const float* __restrict__ Vx,
    const u16* __restrict__ wqb, const u16* __restrict__ wkb,
    const u16* __restrict__ wvb,
    const float* __restrict__ bq, const float* __restrict__ bv,
    u16* __restrict__ qo, u16* __restrict__ ko, u16* __restrict__ vo)
{
    __shared__ __align__(16) u16 sbuf[2][8192];   // [A 128x32 | B 128x32] = 16KB/buf
    const int which = blockIdx.y >> 6;            // 0=Q 1=K 2=V
    const float* X  = (which == 0) ? Qx : (which == 1) ? Kx : Vx;
    const u16*   W  = (which == 0) ? wqb : (which == 1) ? wkb : wvb;
    const float* bias = (which == 0) ? bq : (which == 2) ? bv : nullptr;
    u16* out = (which == 0) ? qo : (which == 1) ? ko : vo;
    const int vt = (which == 2);

    const int tid  = threadIdx.x;
    const int lane = tid & 63;
    const int wave = tid >> 6;
    const int row  = lane & 15;
    const int quad = lane >> 4;
    const int n0 = blockIdx.x * 128;
    const int m0 = (blockIdx.y & 63) * 128;
    const int wm = (wave & 1) * 64;
    const int wn = (wave >> 1) * 64;

    const int srow = tid >> 2;           // 0..63
    const int sch  = tid & 3;            // 8-elem chunk within the 32-elem K-slice
    const float* xg = X + (size_t)(m0 + srow) * DM + sch * 8;
    const u16*   wg = W + (size_t)(n0 + srow) * DM + sch * 8;
    const int swz   = (sch ^ ((srow >> 1) & 3)) * 8;   // write-side swizzle
    const int ldsA  = srow * 32 + swz;
    const int ldsB  = 4096 + ldsA;
    const int rsw   = (quad ^ ((row >> 1) & 3)) * 8;   // read-side swizzle

    {
        float4 a00 = *(const float4*)(xg);
        float4 a01 = *(const float4*)(xg + 4);
        float4 a10 = *(const float4*)(xg + (size_t)64 * DM);
        float4 a11 = *(const float4*)(xg + (size_t)64 * DM + 4);
        uint4 b0 = *(const uint4*)(wg);
        uint4 b1 = *(const uint4*)(wg + (size_t)64 * DM);
        uint4 ac0 = { pk2(a00.x, a00.y), pk2(a00.z, a00.w),
                      pk2(a01.x, a01.y), pk2(a01.z, a01.w) };
        uint4 ac1 = { pk2(a10.x, a10.y), pk2(a10.z, a10.w),
                      pk2(a11.x, a11.y), pk2(a11.z, a11.w) };
        *(uint4*)(&sbuf[0][ldsA])        = ac0;
        *(uint4*)(&sbuf[0][ldsA + 2048]) = ac1;    // row+64
        *(uint4*)(&sbuf[0][ldsB])        = b0;
        *(uint4*)(&sbuf[0][ldsB + 2048]) = b1;
    }

    f32x4 acc[4][4] = {};
    for (int ki = 0; ki < 32; ++ki) {
        __syncthreads();
        const int ktn = (ki == 31) ? 0 : (ki + 1) * 32;
        float4 a00 = *(const float4*)(xg + ktn);
        float4 a01 = *(const float4*)(xg + ktn + 4);
        float4 a10 = *(const float4*)(xg + (size_t)64 * DM + ktn);
        float4 a11 = *(const float4*)(xg + (size_t)64 * DM + ktn + 4);
        uint4 b0 = *(const uint4*)(wg + ktn);
        uint4 b1 = *(const uint4*)(wg + (size_t)64 * DM + ktn);

        const u16* Ab = sbuf[ki & 1];
        const u16* Bb = Ab + 4096;
        bf16x8 af[4], bfr[4];
#pragma unroll
        for (int i = 0; i < 4; i++)
            af[i] = *(const bf16x8*)(Ab + (wm + i * 16 + row) * 32 + rsw);
#pragma unroll
        for (int j = 0; j < 4; j++)
            bfr[j] = *(const bf16x8*)(Bb + (wn + j * 16 + row) * 32 + rsw);
#pragma unroll
        for (int i = 0; i < 4; i++)
#pragma unroll
            for (int j = 0; j < 4; j++)
                acc[i][j] = __builtin_amdgcn_mfma_f32_16x16x32_bf16(af[i], bfr[j], acc[i][j], 0, 0, 0);

        u16* nb = sbuf[(ki + 1) & 1];
        uint4 ac0 = { pk2(a00.x, a00.y), pk2(a00.z, a00.w),
                      pk2(a01.x, a01.y), pk2(a01.z, a01.w) };
        uint4 ac1 = { pk2(a10.x, a10.y), pk2(a10.z, a10.w),
                      pk2(a11.x, a11.y), pk2(a11.z, a11.w) };
        *(uint4*)(nb + ldsA)        = ac0;
        *(uint4*)(nb + ldsA + 2048) = ac1;
        *(uint4*)(nb + ldsB)        = b0;
        *(uint4*)(nb + ldsB + 2048) = b1;
    }

    const int bidx = m0 >> 11;
#pragma unroll
    for (int j = 0; j < 4; j++) {
        const int n = n0 + wn + j * 16 + row;
        const int h = n >> 6;
        const int c = n & (DH - 1);
        const float bvv = bias ? bias[n] : 0.0f;
#pragma unroll
        for (int i = 0; i < 4; i++) {
            const int mbase = m0 + wm + i * 16 + quad * 4;
            const int s = mbase & (SEQ - 1);
            if (vt) {
                ushort4 o = { f2bf(acc[i][j][0] + bvv), f2bf(acc[i][j][1] + bvv),
                              f2bf(acc[i][j][2] + bvv), f2bf(acc[i][j][3] + bvv) };
                size_t idx = (((size_t)(bidx * NH + h) * 32 + (s >> 6)) * DH + c) * 64 + (s & 63);
                *(ushort4*)(out + idx) = o;
            } else {
#pragma unroll
                for (int r = 0; r < 4; r++)
                    out[(size_t)((bidx * NH + h) * SEQ + s + r) * DH + c] = f2bf(acc[i][j][r] + bvv);
            }
        }
    }
}

// Flash attention, transposed-S, no online max. Block = 4 waves x 32 q = 128 q.
// Exact round-0 internals (known good). Added: XCD-chunked blockIdx remap so
// the 16 q-blocks of one head land on one XCD (L2 reuse of K/V panels).
__global__ __launch_bounds__(256, 3) void attn_kernel(
    const u16* __restrict__ qws, const u16* __restrict__ kws,
    const u16* __restrict__ vws, const float* __restrict__ maskf,
    float* __restrict__ out)
{
    __shared__ __align__(16) u16 kbuf[2][64 * 72];   // 9216 B each
    __shared__ __align__(16) u16 vbuf[2][64 * 72];   // rows = dh, cols = key
    const int tid  = threadIdx.x;
    const int lane = tid & 63;
    const int wave = tid >> 6;
    const int row  = lane & 15;
    const int quad = lane >> 4;
    // bijective XCD-chunk remap: 1024 blocks, 8 XCDs -> 128 contiguous
    // logical blocks (= 8 whole heads) per XCD
    const int bid0 = blockIdx.x;
    const int bid  = ((bid0 & 7) << 7) | (bid0 >> 3);
    const int qb = bid & 15;            // SEQ/128 = 16
    const int h  = (bid >> 4) & (NH - 1);
    const int b  = bid >> 8;
    const int q0 = qb * 128 + wave * 32;

    const u16* qbase = qws + (size_t)(b * NH + h) * SEQ * DH;
    const u16* kbase = kws + (size_t)(b * NH + h) * SEQ * DH;
    const u16* vtb   = vws + (size_t)(b * NH + h) * 32 * (DH * 64); // tile-blocked
    const float* mrow = maskf + b * SEQ;

    // K staging: thread t covers rows srow, srow+32 of the 64x64 K tile
    const int srow = tid >> 3;          // 0..31
    const int scol = (tid & 7) * 8;
    const u16* kgp = kbase + (size_t)srow * DH + scol;
    const int ldso = srow * 72 + scol;
    // V staging: contiguous 8KB tile; chunk tid -> lds row tid>>3 col (tid&7)*8
    const int vldso = ldso;             // same decomposition

    // Q fragments, 2 groups of 16 queries
    bf16x8 qf[2][2];
#pragma unroll
    for (int gi = 0; gi < 2; gi++) {
        qf[gi][0] = *(const bf16x8*)(qbase + (size_t)(q0 + gi * 16 + row) * DH + quad * 8);
        qf[gi][1] = *(const bf16x8*)(qbase + (size_t)(q0 + gi * 16 + row) * DH + 32 + quad * 8);
    }

    f32x4 O[2][4] = {};
    float lrun[2] = {0.0f, 0.0f};

    // preload tile 0
    {
        uint4 k0 = *(const uint4*)(kgp);
        uint4 k1 = *(const uint4*)(kgp + (size_t)32 * DH);
        uint4 v0 = *(const uint4*)(vtb + tid * 8);
        uint4 v1 = *(const uint4*)(vtb + (tid + 256) * 8);
        *(uint4*)(&kbuf[0][ldso])            = k0;
        *(uint4*)(&kbuf[0][32 * 72 + ldso])  = k1;
        *(uint4*)(&vbuf[0][vldso])           = v0;
        *(uint4*)(&vbuf[0][32 * 72 + vldso]) = v1;
    }

    for (int it = 0; it < 32; ++it) {
        const int kt = it * 64;
        __syncthreads();
        // (1) mask loads FIRST (softmax waits only these + older)
        float4 mk[4];
#pragma unroll
        for (int g = 0; g < 4; g++)
            mk[g] = *(const float4*)(mrow + kt + g * 16 + quad * 4);
        // (2) next-tile prefetch (wrap on last iter; values unused)
        const int itn = (it == 31) ? 0 : it + 1;
        uint4 kr0 = *(const uint4*)(kgp + (size_t)itn * 64 * DH);
        uint4 kr1 = *(const uint4*)(kgp + (size_t)(itn * 64 + 32) * DH);
        uint4 vr0 = *(const uint4*)(vtb + (size_t)itn * 4096 + tid * 8);
        uint4 vr1 = *(const uint4*)(vtb + (size_t)itn * 4096 + (tid + 256) * 8);

        // S^T = K·Q^T from LDS
        const u16* kb = kbuf[it & 1];
        f32x4 st[2][4] = {};
#pragma unroll
        for (int g = 0; g < 4; g++) {
#pragma unroll
            for (int ks = 0; ks < 2; ks++) {
                bf16x8 kf = *(const bf16x8*)(kb + (g * 16 + row) * 72 + ks * 32 + quad * 8);
                st[0][g] = __builtin_amdgcn_mfma_f32_16x16x32_bf16(kf, qf[0][ks], st[0][g], 0, 0, 0);
                st[1][g] = __builtin_amdgcn_mfma_f32_16x16x32_bf16(kf, qf[1][ks], st[1][g], 0, 0, 0);
            }
        }

        // P = exp2(st*SCL2 + m2); masked -> exactly 0. No max, no rescale.
        union { u32 u[2]; bf16x4 v; } pw[2][4];
#pragma unroll
        for (int gi = 0; gi < 2; gi++) {
            float lsum = 0.0f;
#pragma unroll
            for (int g = 0; g < 4; g++) {
                float p0 = fexp2(fmaf(st[gi][g][0], SCL2, mk[g].x));
                float p1 = fexp2(fmaf(st[gi][g][1], SCL2, mk[g].y));
                float p2 = fexp2(fmaf(st[gi][g][2], SCL2, mk[g].z));
                float p3 = fexp2(fmaf(st[gi][g][3], SCL2, mk[g].w));
                lsum += (p0 + p1) + (p2 + p3);
                pw[gi][g].u[0] = packbf(p0, p1);
                pw[gi][g].u[1] = packbf(p2, p3);
            }
            lsum += __shfl_xor(lsum, 16, 64);
            lsum += __shfl_xor(lsum, 32, 64);
            lrun[gi] += lsum;
        }

        // O^T += V^T · P^T; V frags from LDS (b64, conflict-floor)
        const u16* vb = vbuf[it & 1];
#pragma unroll
        for (int dg = 0; dg < 4; dg++) {
#pragma unroll
            for (int g = 0; g < 4; g++) {
                bf16x4 vfrag = *(const bf16x4*)(vb + (dg * 16 + row) * 72 + g * 16 + quad * 4);
                O[0][dg] = pv_mfma(vfrag, pw[0][g].v, O[0][dg]);
                O[1][dg] = pv_mfma(vfrag, pw[1][g].v, O[1][dg]);
            }
        }

        // stage next tile (vmcnt(0) here is covered by the compute above)
        u16* nkb = kbuf[(it + 1) & 1];
        u16* nvb = vbuf[(it + 1) & 1];
        *(uint4*)(nkb + ldso)             = kr0;
        *(uint4*)(nkb + 32 * 72 + ldso)   = kr1;
        *(uint4*)(nvb + vldso)            = vr0;
        *(uint4*)(nvb + 32 * 72 + vldso)  = vr1;
    }

#pragma unroll
    for (int gi = 0; gi < 2; gi++) {
        const float rl = 1.0f / lrun[gi];
        const int q = q0 + gi * 16 + row;
#pragma unroll
        for (int dg = 0; dg < 4; dg++) {
            float4 o4 = { O[gi][dg][0] * rl, O[gi][dg][1] * rl,
                          O[gi][dg][2] * rl, O[gi][dg][3] * rl };
            *(float4*)(out + (size_t)(b * SEQ + q) * (NH * DH) + h * DH + dg * 16 + quad * 4) = o4;
        }
    }
}

extern "C" void kernel_launch(void* const* d_in, const int* in_sizes, int n_in,
                              void* d_out, int out_size, void* d_ws, size_t ws_size,
                              hipStream_t stream) {
    const float* Q    = (const float*)d_in[0];
    const float* K    = (const float*)d_in[1];
    const float* V    = (const float*)d_in[2];
    const int*   mask = (const int*)d_in[3];
    const float* Wq   = (const float*)d_in[4];
    const float* bq   = (const float*)d_in[5];
    const float* Wk   = (const float*)d_in[6];
    const float* Wv   = (const float*)d_in[7];
    const float* bv   = (const float*)d_in[8];
    float* out = (float*)d_out;

    const size_t XN = (size_t)NB * SEQ * DM;     // 8,388,608
    const size_t WN = (size_t)DM * DM;           // 1,048,576
    u16* ws = (u16*)d_ws;
    u16* wqb  = ws;
    u16* wkb  = wqb + WN;
    u16* wvb  = wkb + WN;
    u16* qws  = wvb + WN;
    u16* kws  = qws + XN;
    u16* vws  = kws + XN;
    float* maskf = (float*)(vws + XN);           // 8192 floats; ws ~56.7 MB

    dim3 blk(256);
    prep_kernel<<<3072 + 32, blk, 0, stream>>>(Wq, Wk, Wv, mask, wqb, wkb, wvb, maskf);

    // all three projections in one launch: grid (8, 192) = 1536 blocks
    proj_kernel<<<dim3(DM / 128, 192), blk, 0, stream>>>(
        Q, K, V, wqb, wkb, wvb, bq, bv, qws, kws, vws);

    attn_kernel<<<dim3(NB * NH * (SEQ / 128)), blk, 0, stream>>>(qws, kws, vws, maskf, out);
}

// Round 3
// 360.467 us; speedup vs baseline: 1.0392x; 1.0392x over previous
//
#include <hip/hip_runtime.h>
#include <stdint.h>
#include <math.h>

#define NH 16
#define DM 1024
#define SEQ 2048
#define DH 64
#define NB 4
// -1e9 premultiplied by log2(e): masked score -> exp2(-1.44e9) == 0
#define NEG2 (-1.4426950408889634e9f)
// (1/8) * log2(e)
#define SCL2 (0.18033688011112042f)

typedef __attribute__((ext_vector_type(8))) short bf16x8;
typedef __attribute__((ext_vector_type(4))) short bf16x4;
typedef __attribute__((ext_vector_type(4))) float f32x4;
typedef unsigned short u16;
typedef uint32_t u32;

__device__ __forceinline__ u16 f2bf(float f) {     // RNE
    union { float f; u32 i; } c; c.f = f;
    u32 r = c.i + 0x7fffu + ((c.i >> 16) & 1u);
    return (u16)(r >> 16);
}
// pack two f32 -> bf16x2 via RNE (pure C; no inline asm)
__device__ __forceinline__ u32 pk2(float lo, float hi) {
    return (u32)f2bf(lo) | ((u32)f2bf(hi) << 16);
}
// pack two f32 -> bf16x2 (round-half-up; inputs are exp() results, finite >=0)
__device__ __forceinline__ u32 packbf(float lo, float hi) {
    union { float f; u32 i; } a, b; a.f = lo; b.f = hi;
    return ((a.i + 0x8000u) >> 16) | ((b.i + 0x8000u) & 0xFFFF0000u);
}

__device__ __forceinline__ float fexp2(float x) {
#if __has_builtin(__builtin_amdgcn_exp2f)
    return __builtin_amdgcn_exp2f(x);
#else
    return exp2f(x);
#endif
}

__device__ __forceinline__ f32x4 pv_mfma(bf16x4 a, bf16x4 b, f32x4 c) {
#if __has_builtin(__builtin_amdgcn_mfma_f32_16x16x16bf16_1k)
    return __builtin_amdgcn_mfma_f32_16x16x16bf16_1k(a, b, c, 0, 0, 0);
#else
    f32x4 d;
    asm volatile("s_nop 1\n\t"
                 "v_mfma_f32_16x16x16_bf16 %0, %1, %2, %3\n\t"
                 "s_nop 7\n\t"
                 "s_nop 7"
                 : "=v"(d) : "v"(a), "v"(b), "v"(c));
    return d;
#endif
}

// fused: convert Wq,Wk,Wv (f32->bf16) + build mask floats. 3*1024 + 32 blocks.
__global__ __launch_bounds__(256) void prep_kernel(
    const float* __restrict__ Wq, const float* __restrict__ Wk,
    const float* __restrict__ Wv, const int* __restrict__ mask,
    u16* __restrict__ wqb, u16* __restrict__ wkb, u16* __restrict__ wvb,
    float* __restrict__ mf) {
    const int bid = blockIdx.x;
    if (bid < 3072) {
        const float* src = (bid < 1024) ? Wq : (bid < 2048) ? Wk : Wv;
        u16* dst = (bid < 1024) ? wqb : (bid < 2048) ? wkb : wvb;
        int i = (bid & 1023) * 256 + threadIdx.x;
        float4 v = ((const float4*)src)[i];
        ushort4 o = { f2bf(v.x), f2bf(v.y), f2bf(v.z), f2bf(v.w) };
        ((ushort4*)dst)[i] = o;
    } else {
        int i = (bid - 3072) * 256 + threadIdx.x;   // 32 blocks * 256 = 8192
        mf[i] = mask[i] ? 0.0f : NEG2;
    }
}

// Merged projection, XCD-locality remap. 1536 blocks; physical linear id p
// round-robins XCDs (p&7). Remap so XCD k owns m-panels [24k,24k+24), with
// the 8 n-tiles of one m-panel CONSECUTIVE on that XCD: X panel (512KB f32)
// is fetched once into the XCD's L2 and reused by all 8 n-tiles; the active
// W matrix (2MB bf16) stays L2-resident across m-panels.
// C[8192,1024] = X[8192,1024](f32)*W[1024,1024]^T(bf16) (+bias), bf16 out.
// 128x128 tile, BK=32, LDS double-buffer, one barrier/iter, X converted
// f32->bf16 during staging. LDS XOR swizzle (chunk ^= (row>>1)&3).
// which==2 (V): tile-blocked out[(((b*NH+h)*32+(s>>6))*DH+c)*64 + (s&63)]
__global__ __launch_bounds__(256, 3) void proj_kernel(
    const float* __restrict__ Qx, const float* __restrict__ Kx,
    const float* __restrict__ Vx,
    const u16* __restrict__ wqb, const u16* __restrict__ wkb,
    const u16* __restrict__ wvb,
    const float* __restrict__ bq, const float* __restrict__ bv,
    u16* __restrict__ qo, u16* __restrict__ ko, u16* __restrict__ vo)
{
    __shared__ __align__(16) u16 sbuf[2][8192];   // [A 128x32 | B 128x32] = 16KB/buf
    // ---- bijective XCD-chunk remap ----
    const int p   = blockIdx.y * 8 + blockIdx.x;  // physical linear, x fastest
    const int xcd = p & 7;
    const int i8  = p >> 3;                       // 0..191
    const int ly  = xcd * 24 + (i8 >> 3);         // logical m-panel 0..191
    const int lx  = i8 & 7;                       // logical n-tile 0..7

    const int which = ly >> 6;                    // 0=Q 1=K 2=V
    const float* X  = (which == 0) ? Qx : (which == 1) ? Kx : Vx;
    const u16*   W  = (which == 0) ? wqb : (which == 1) ? wkb : wvb;
    const float* bias = (which == 0) ? bq : (which == 2) ? bv : nullptr;
    u16* out = (which == 0) ? qo : (which == 1) ? ko : vo;
    const int vt = (which == 2);

    const int tid  = threadIdx.x;
    const int lane = tid & 63;
    const int wave = tid >> 6;
    const int row  = lane & 15;
    const int quad = lane >> 4;
    const int n0 = lx * 128;
    const int m0 = (ly & 63) * 128;
    const int wm = (wave & 1) * 64;
    const int wn = (wave >> 1) * 64;

    const int srow = tid >> 2;           // 0..63
    const int sch  = tid & 3;            // 8-elem chunk within the 32-elem K-slice
    const float* xg = X + (size_t)(m0 + srow) * DM + sch * 8;
    const u16*   wg = W + (size_t)(n0 + srow) * DM + sch * 8;
    const int swz   = (sch ^ ((srow >> 1) & 3)) * 8;   // write-side swizzle
    const int ldsA  = srow * 32 + swz;
    const int ldsB  = 4096 + ldsA;
    const int rsw   = (quad ^ ((row >> 1) & 3)) * 8;   // read-side swizzle

    {
        float4 a00 = *(const float4*)(xg);
        float4 a01 = *(const float4*)(xg + 4);
        float4 a10 = *(const float4*)(xg + (size_t)64 * DM);
        float4 a11 = *(const float4*)(xg + (size_t)64 * DM + 4);
        uint4 b0 = *(const uint4*)(wg);
        uint4 b1 = *(const uint4*)(wg + (size_t)64 * DM);
        uint4 ac0 = { pk2(a00.x, a00.y), pk2(a00.z, a00.w),
                      pk2(a01.x, a01.y), pk2(a01.z, a01.w) };
        uint4 ac1 = { pk2(a10.x, a10.y), pk2(a10.z, a10.w),
                      pk2(a11.x, a11.y), pk2(a11.z, a11.w) };
        *(uint4*)(&sbuf[0][ldsA])        = ac0;
        *(uint4*)(&sbuf[0][ldsA + 2048]) = ac1;    // row+64
        *(uint4*)(&sbuf[0][ldsB])        = b0;
        *(uint4*)(&sbuf[0][ldsB + 2048]) = b1;
    }

    f32x4 acc[4][4] = {};
    for (int ki = 0; ki < 32; ++ki) {
        __syncthreads();
        const int ktn = (ki == 31) ? 0 : (ki + 1) * 32;
        float4 a00 = *(const float4*)(xg + ktn);
        float4 a01 = *(const float4*)(xg + ktn + 4);
        float4 a10 = *(const float4*)(xg + (size_t)64 * DM + ktn);
        float4 a11 = *(const float4*)(xg + (size_t)64 * DM + ktn + 4);
        uint4 b0 = *(const uint4*)(wg + ktn);
        uint4 b1 = *(const uint4*)(wg + (size_t)64 * DM + ktn);

        const u16* Ab = sbuf[ki & 1];
        const u16* Bb = Ab + 4096;
        bf16x8 af[4], bfr[4];
#pragma unroll
        for (int i = 0; i < 4; i++)
            af[i] = *(const bf16x8*)(Ab + (wm + i * 16 + row) * 32 + rsw);
#pragma unroll
        for (int j = 0; j < 4; j++)
            bfr[j] = *(const bf16x8*)(Bb + (wn + j * 16 + row) * 32 + rsw);
#pragma unroll
        for (int i = 0; i < 4; i++)
#pragma unroll
            for (int j = 0; j < 4; j++)
                acc[i][j] = __builtin_amdgcn_mfma_f32_16x16x32_bf16(af[i], bfr[j], acc[i][j], 0, 0, 0);

        u16* nb = sbuf[(ki + 1) & 1];
        uint4 ac0 = { pk2(a00.x, a00.y), pk2(a00.z, a00.w),
                      pk2(a01.x, a01.y), pk2(a01.z, a01.w) };
        uint4 ac1 = { pk2(a10.x, a10.y), pk2(a10.z, a10.w),
                      pk2(a11.x, a11.y), pk2(a11.z, a11.w) };
        *(uint4*)(nb + ldsA)        = ac0;
        *(uint4*)(nb + ldsA + 2048) = ac1;
        *(uint4*)(nb + ldsB)        = b0;
        *(uint4*)(nb + ldsB + 2048) = b1;
    }

    const int bidx = m0 >> 11;
#pragma unroll
    for (int j = 0; j < 4; j++) {
        const int n = n0 + wn + j * 16 + row;
        const int h = n >> 6;
        const int c = n & (DH - 1);
        const float bvv = bias ? bias[n] : 0.0f;
#pragma unroll
        for (int i = 0; i < 4; i++) {
            const int mbase = m0 + wm + i * 16 + quad * 4;
            const int s = mbase & (SEQ - 1);
            if (vt) {
                ushort4 o = { f2bf(acc[i][j][0] + bvv), f2bf(acc[i][j][1] + bvv),
                              f2bf(acc[i][j][2] + bvv), f2bf(acc[i][j][3] + bvv) };
                size_t idx = (((size_t)(bidx * NH + h) * 32 + (s >> 6)) * DH + c) * 64 + (s & 63);
                *(ushort4*)(out + idx) = o;
            } else {
#pragma unroll
                for (int r = 0; r < 4; r++)
                    out[(size_t)((bidx * NH + h) * SEQ + s + r) * DH + c] = f2bf(acc[i][j][r] + bvv);
            }
        }
    }
}

// Flash attention, transposed-S, no online max. Block = 4 waves x 32 q = 128 q.
// Byte-exact round-0 kernel (119.7 us known good); identity block order —
// the XCD-chunked remap measured ~+70us (L2 thrash at 4MB/XCD working set).
__global__ __launch_bounds__(256, 3) void attn_kernel(
    const u16* __restrict__ qws, const u16* __restrict__ kws,
    const u16* __restrict__ vws, const float* __restrict__ maskf,
    float* __restrict__ out)
{
    __shared__ __align__(16) u16 kbuf[2][64 * 72];   // 9216 B each
    __shared__ __align__(16) u16 vbuf[2][64 * 72];   // rows = dh, cols = key
    const int tid  = threadIdx.x;
    const int lane = tid & 63;
    const int wave = tid >> 6;
    const int row  = lane & 15;
    const int quad = lane >> 4;
    const int bid = blockIdx.x;
    const int qb = bid & 15;            // SEQ/128 = 16
    const int h  = (bid >> 4) & (NH - 1);
    const int b  = bid >> 8;
    const int q0 = qb * 128 + wave * 32;

    const u16* qbase = qws + (size_t)(b * NH + h) * SEQ * DH;
    const u16* kbase = kws + (size_t)(b * NH + h) * SEQ * DH;
    const u16* vtb   = vws + (size_t)(b * NH + h) * 32 * (DH * 64); // tile-blocked
    const float* mrow = maskf + b * SEQ;

    // K staging: thread t covers rows srow, srow+32 of the 64x64 K tile
    const int srow = tid >> 3;          // 0..31
    const int scol = (tid & 7) * 8;
    const u16* kgp = kbase + (size_t)srow * DH + scol;
    const int ldso = srow * 72 + scol;
    // V staging: contiguous 8KB tile; chunk tid -> lds row tid>>3 col (tid&7)*8
    const int vldso = ldso;             // same decomposition

    // Q fragments, 2 groups of 16 queries
    bf16x8 qf[2][2];
#pragma unroll
    for (int gi = 0; gi < 2; gi++) {
        qf[gi][0] = *(const bf16x8*)(qbase + (size_t)(q0 + gi * 16 + row) * DH + quad * 8);
        qf[gi][1] = *(const bf16x8*)(qbase + (size_t)(q0 + gi * 16 + row) * DH + 32 + quad * 8);
    }

    f32x4 O[2][4] = {};
    float lrun[2] = {0.0f, 0.0f};

    // preload tile 0
    {
        uint4 k0 = *(const uint4*)(kgp);
        uint4 k1 = *(const uint4*)(kgp + (size_t)32 * DH);
        uint4 v0 = *(const uint4*)(vtb + tid * 8);
        uint4 v1 = *(const uint4*)(vtb + (tid + 256) * 8);
        *(uint4*)(&kbuf[0][ldso])            = k0;
        *(uint4*)(&kbuf[0][32 * 72 + ldso])  = k1;
        *(uint4*)(&vbuf[0][vldso])           = v0;
        *(uint4*)(&vbuf[0][32 * 72 + vldso]) = v1;
    }

    for (int it = 0; it < 32; ++it) {
        const int kt = it * 64;
        __syncthreads();
        // (1) mask loads FIRST (softmax waits only these + older)
        float4 mk[4];
#pragma unroll
        for (int g = 0; g < 4; g++)
            mk[g] = *(const float4*)(mrow + kt + g * 16 + quad * 4);
        // (2) next-tile prefetch (wrap on last iter; values unused)
        const int itn = (it == 31) ? 0 : it + 1;
        uint4 kr0 = *(const uint4*)(kgp + (size_t)itn * 64 * DH);
        uint4 kr1 = *(const uint4*)(kgp + (size_t)(itn * 64 + 32) * DH);
        uint4 vr0 = *(const uint4*)(vtb + (size_t)itn * 4096 + tid * 8);
        uint4 vr1 = *(const uint4*)(vtb + (size_t)itn * 4096 + (tid + 256) * 8);

        // S^T = K·Q^T from LDS
        const u16* kb = kbuf[it & 1];
        f32x4 st[2][4] = {};
#pragma unroll
        for (int g = 0; g < 4; g++) {
#pragma unroll
            for (int ks = 0; ks < 2; ks++) {
                bf16x8 kf = *(const bf16x8*)(kb + (g * 16 + row) * 72 + ks * 32 + quad * 8);
                st[0][g] = __builtin_amdgcn_mfma_f32_16x16x32_bf16(kf, qf[0][ks], st[0][g], 0, 0, 0);
                st[1][g] = __builtin_amdgcn_mfma_f32_16x16x32_bf16(kf, qf[1][ks], st[1][g], 0, 0, 0);
            }
        }

        // P = exp2(st*SCL2 + m2); masked -> exactly 0. No max, no rescale.
        union { u32 u[2]; bf16x4 v; } pw[2][4];
#pragma unroll
        for (int gi = 0; gi < 2; gi++) {
            float lsum = 0.0f;
#pragma unroll
            for (int g = 0; g < 4; g++) {
                float p0 = fexp2(fmaf(st[gi][g][0], SCL2, mk[g].x));
                float p1 = fexp2(fmaf(st[gi][g][1], SCL2, mk[g].y));
                float p2 = fexp2(fmaf(st[gi][g][2], SCL2, mk[g].z));
                float p3 = fexp2(fmaf(st[gi][g][3], SCL2, mk[g].w));
                lsum += (p0 + p1) + (p2 + p3);
                pw[gi][g].u[0] = packbf(p0, p1);
                pw[gi][g].u[1] = packbf(p2, p3);
            }
            lsum += __shfl_xor(lsum, 16, 64);
            lsum += __shfl_xor(lsum, 32, 64);
            lrun[gi] += lsum;
        }

        // O^T += V^T · P^T; V frags from LDS (b64, conflict-floor)
        const u16* vb = vbuf[it & 1];
#pragma unroll
        for (int dg = 0; dg < 4; dg++) {
#pragma unroll
            for (int g = 0; g < 4; g++) {
                bf16x4 vfrag = *(const bf16x4*)(vb + (dg * 16 + row) * 72 + g * 16 + quad * 4);
                O[0][dg] = pv_mfma(vfrag, pw[0][g].v, O[0][dg]);
                O[1][dg] = pv_mfma(vfrag, pw[1][g].v, O[1][dg]);
            }
        }

        // stage next tile (vmcnt(0) here is covered by the compute above)
        u16* nkb = kbuf[(it + 1) & 1];
        u16* nvb = vbuf[(it + 1) & 1];
        *(uint4*)(nkb + ldso)             = kr0;
        *(uint4*)(nkb + 32 * 72 + ldso)   = kr1;
        *(uint4*)(nvb + vldso)            = vr0;
        *(uint4*)(nvb + 32 * 72 + vldso)  = vr1;
    }

#pragma unroll
    for (int gi = 0; gi < 2; gi++) {
        const float rl = 1.0f / lrun[gi];
        const int q = q0 + gi * 16 + row;
#pragma unroll
        for (int dg = 0; dg < 4; dg++) {
            float4 o4 = { O[gi][dg][0] * rl, O[gi][dg][1] * rl,
                          O[gi][dg][2] * rl, O[gi][dg][3] * rl };
            *(float4*)(out + (size_t)(b * SEQ + q) * (NH * DH) + h * DH + dg * 16 + quad * 4) = o4;
        }
    }
}

extern "C" void kernel_launch(void* const* d_in, const int* in_sizes, int n_in,
                              void* d_out, int out_size, void* d_ws, size_t ws_size,
                              hipStream_t stream) {
    const float* Q    = (const float*)d_in[0];
    const float* K    = (const float*)d_in[1];
    const float* V    = (const float*)d_in[2];
    const int*   mask = (const int*)d_in[3];
    const float* Wq   = (const float*)d_in[4];
    const float* bq   = (const float*)d_in[5];
    const float* Wk   = (const float*)d_in[6];
    const float* Wv   = (const float*)d_in[7];
    const float* bv   = (const float*)d_in[8];
    float* out = (float*)d_out;

    const size_t XN = (size_t)NB * SEQ * DM;     // 8,388,608
    const size_t WN = (size_t)DM * DM;           // 1,048,576
    u16* ws = (u16*)d_ws;
    u16* wqb  = ws;
    u16* wkb  = wqb + WN;
    u16* wvb  = wkb + WN;
    u16* qws  = wvb + WN;
    u16* kws  = qws + XN;
    u16* vws  = kws + XN;
    float* maskf = (float*)(vws + XN);           // 8192 floats; ws ~56.7 MB

    dim3 blk(256);
    prep_kernel<<<3072 + 32, blk, 0, stream>>>(Wq, Wk, Wv, mask, wqb, wkb, wvb, maskf);

    // all three projections in one launch: grid (8, 192) = 1536 blocks
    proj_kernel<<<dim3(DM / 128, 192), blk, 0, stream>>>(
        Q, K, V, wqb, wkb, wvb, bq, bv, qws, kws, vws);

    attn_kernel<<<dim3(NB * NH * (SEQ / 128)), blk, 0, stream>>>(qws, kws, vws, maskf, out);
}